// Round 1
// baseline (8624.846 us; speedup 1.0000x reference)
//
#include <hip/hip_runtime.h>
#include <math.h>

#define BLOCK 128

// LDS swizzle: slot(t,k) = t*128 + ((k+t)&127)  -> bank = (k+t)%32, 2 lanes/bank (free)
__device__ __forceinline__ int hidx(int t, int k) { return t * 128 + ((k + t) & 127); }

template <int IN, int OUT, bool WB>
__device__ __forceinline__ void layerf(const float* __restrict__ W,
                                       const float* __restrict__ bia,
                                       float* __restrict__ hbuf, int tid,
                                       float* __restrict__ o) {
    constexpr int NC = (OUT + 31) / 32;
#pragma unroll
    for (int c = 0; c < NC; ++c) {
        constexpr int base_last = (NC - 1) * 32;
        const int cbase = c * 32;
        const int cw = (OUT - cbase < 32) ? (OUT - cbase) : 32;
        (void)base_last;
#pragma unroll
        for (int jj = 0; jj < 32; ++jj) {
            if (jj < cw) o[cbase + jj] = bia[cbase + jj];
        }
        for (int k = 0; k < IN; ++k) {
            const float hk = hbuf[hidx(tid, k)];
            const float* Wr = W + k * OUT + cbase;
#pragma unroll
            for (int jj = 0; jj < 32; ++jj) {
                if (jj < cw) o[cbase + jj] = fmaf(hk, Wr[jj], o[cbase + jj]);
            }
        }
    }
    if (WB) {
#pragma unroll
        for (int k = 0; k < OUT; ++k) hbuf[hidx(tid, k)] = fmaxf(o[k], 0.0f);
    }
}

__global__ __launch_bounds__(BLOCK, 1) void snarf_kernel(
    const float* __restrict__ xin, const float* __restrict__ bone_pts,
    const float* __restrict__ transforms, const float* __restrict__ delta_tf,
    const float* __restrict__ W0, const float* __restrict__ b0,
    const float* __restrict__ W1, const float* __restrict__ b1,
    const float* __restrict__ W2, const float* __restrict__ b2,
    const float* __restrict__ W3, const float* __restrict__ b3,
    const float* __restrict__ W4, const float* __restrict__ b4,
    float* __restrict__ out, int Npts) {
    __shared__ float hbuf[BLOCK * 128];  // 64 KiB
    const int tid = threadIdx.x;
    const int m = blockIdx.x * BLOCK + tid;
    const int M = Npts * 6;
    if (m >= M) return;
    const int n = m / 6;
    const int i = m - n * 6;

    const float tx = xin[n * 3 + 0], ty = xin[n * 3 + 1], tz = xin[n * 3 + 2];

    // ---- init candidate: i<5 -> i-th nearest bone's delta transform; i==5 -> identity
    float xk0, xk1, xk2;
    if (i < 5) {
        float dprev = -1.0f;
        int jprev = -1;
        for (int r = 0; r <= i; ++r) {
            float bd = 3.4028235e38f;
            int bj = 0;
            for (int j = 0; j < 24; ++j) {
                const float ax = tx - bone_pts[j * 3 + 0];
                const float ay = ty - bone_pts[j * 3 + 1];
                const float az = tz - bone_pts[j * 3 + 2];
                const float d = sqrtf(ax * ax + ay * ay + az * az);
                const bool taken = (d < dprev) || (d == dprev && j <= jprev);
                if (!taken && d < bd) { bd = d; bj = j; }
            }
            dprev = bd;
            jprev = bj;
        }
        const float* T = delta_tf + jprev * 16;
        xk0 = fmaf(T[0], tx, fmaf(T[1], ty, fmaf(T[2], tz, T[3])));
        xk1 = fmaf(T[4], tx, fmaf(T[5], ty, fmaf(T[6], tz, T[7])));
        xk2 = fmaf(T[8], tx, fmaf(T[9], ty, fmaf(T[10], tz, T[11])));
    } else {
        xk0 = tx; xk1 = ty; xk2 = tz;
    }

    // ---- Broyden state
    float gx0 = 0.f, gx1 = 0.f, gx2 = 0.f;
    float J00 = 1.f, J01 = 0.f, J02 = 0.f;
    float J10 = 0.f, J11 = 1.f, J12 = 0.f;
    float J20 = 0.f, J21 = 0.f, J22 = 1.f;
    float up0 = 0.f, up1 = 0.f, up2 = 0.f;
    float xo0 = xk0, xo1 = xk1, xo2 = xk2;
    float nopt = 0.f;
    float dx0 = 0.f, dx1 = 0.f, dx2 = 0.f;
    float dg0 = 0.f, dg1 = 0.f, dg2 = 0.f;
    bool mask = true;

    float o[128];

    int step = -1;  // -1 = init eval, 0..7 = Broyden steps, 8 = final eval
    while (step <= 8) {
        bool m3 = mask;
        if (step >= 0 && step < 8) {
            if (__ballot(mask) == 0ull) { step = 8; m3 = mask; continue; }
            if (m3) {
                dx0 = up0; dx1 = up1; dx2 = up2;
                xk0 += dx0; xk1 += dx1; xk2 += dx2;
            }
        }
        float cx0 = xk0, cx1 = xk1, cx2 = xk2;
        if (step == 8) { cx0 = xo0; cx1 = xo1; cx2 = xo2; }

        // ======== g eval at (cx0,cx1,cx2) ========
        // positional encoding -> LDS h[0..26]
        hbuf[hidx(tid, 0)] = cx0;
        hbuf[hidx(tid, 1)] = cx1;
        hbuf[hidx(tid, 2)] = cx2;
#pragma unroll
        for (int s = 0; s < 4; ++s) {
            const float sc = (float)(1 << s);
            float s0, c0, s1, c1, s2, c2;
            sincosf(sc * cx0, &s0, &c0);
            sincosf(sc * cx1, &s1, &c1);
            sincosf(sc * cx2, &s2, &c2);
            hbuf[hidx(tid, 3 + s * 3 + 0)] = s0;
            hbuf[hidx(tid, 3 + s * 3 + 1)] = s1;
            hbuf[hidx(tid, 3 + s * 3 + 2)] = s2;
            hbuf[hidx(tid, 15 + s * 3 + 0)] = c0;
            hbuf[hidx(tid, 15 + s * 3 + 1)] = c1;
            hbuf[hidx(tid, 15 + s * 3 + 2)] = c2;
        }
        layerf<27, 128, true>(W0, b0, hbuf, tid, o);
        layerf<128, 128, true>(W1, b1, hbuf, tid, o);
        layerf<128, 128, true>(W2, b2, hbuf, tid, o);
        layerf<128, 128, true>(W3, b3, hbuf, tid, o);
        layerf<128, 25, false>(W4, b4, hbuf, tid, o);

        // softmax(5 * logits) over 25
        float zm = -3.4028235e38f;
#pragma unroll
        for (int j = 0; j < 25; ++j) {
            o[j] = 5.0f * o[j];
            zm = fmaxf(zm, o[j]);
        }
        float ssum = 0.f;
#pragma unroll
        for (int j = 0; j < 25; ++j) {
            o[j] = expf(o[j] - zm);
            ssum += o[j];
        }
        const float inv = 1.0f / ssum;

        // blend transforms: tf[3][4] = sum_j w_j * Tfull_j[:3,:4]
        float tf[12];
#pragma unroll
        for (int r = 0; r < 12; ++r) tf[r] = 0.f;
#pragma unroll
        for (int j = 0; j < 24; ++j) {
            const float wj = o[j] * inv;
            const float* T = transforms + j * 16;
#pragma unroll
            for (int r = 0; r < 12; ++r) tf[r] = fmaf(wj, T[r], tf[r]);
        }
        {
            const float wj = o[24] * inv;  // identity transform
            tf[0] += wj; tf[5] += wj; tf[10] += wj;
        }
        const float r0 = fmaf(tf[0], cx0, fmaf(tf[1], cx1, fmaf(tf[2], cx2, tf[3])));
        const float r1 = fmaf(tf[4], cx0, fmaf(tf[5], cx1, fmaf(tf[6], cx2, tf[7])));
        const float r2 = fmaf(tf[8], cx0, fmaf(tf[9], cx1, fmaf(tf[10], cx2, tf[11])));
        // ======== end g eval ========

        if (step == 8) {
            out[(size_t)m * 3 + 0] = r0;
            out[(size_t)m * 3 + 1] = r1;
            out[(size_t)m * 3 + 2] = r2;
            float* xopt_out = out + (size_t)M * 3;
            xopt_out[(size_t)m * 3 + 0] = xo0;
            xopt_out[(size_t)m * 3 + 1] = xo1;
            xopt_out[(size_t)m * 3 + 2] = xo2;
            out[(size_t)M * 6 + m] = nopt;
            out[(size_t)M * 7 + m] = (nopt < 1e-5f) ? 1.0f : 0.0f;
            break;
        }

        const float g0 = r0 - tx, g1 = r1 - ty, g2 = r2 - tz;

        if (step == -1) {
            gx0 = g0; gx1 = g1; gx2 = g2;
            const float gn = sqrtf(g0 * g0 + g1 * g1 + g2 * g2);
            nopt = gn;
            up0 = -g0; up1 = -g1; up2 = -g2;  // Jinv = I
            // xopt already x0, mask already true, dx=dg=0
        } else {
            if (m3) {
                dg0 = g0 - gx0; dg1 = g1 - gx1; dg2 = g2 - gx2;
                gx0 += dg0; gx1 += dg1; gx2 += dg2;
            }
            const float gn = sqrtf(gx0 * gx0 + gx1 * gx1 + gx2 * gx2);
            const bool better = gn < nopt;
            if (better) {
                nopt = gn;
                xo0 = xk0; xo1 = xk1; xo2 = xk2;
            }
            mask = (nopt > 1e-5f) && (gn < 1.0f);

            // vT = dx^T @ Jinv
            const float v0 = dx0 * J00 + dx1 * J10 + dx2 * J20;
            const float v1 = dx0 * J01 + dx1 * J11 + dx2 * J21;
            const float v2 = dx0 * J02 + dx1 * J12 + dx2 * J22;
            // Jinv @ dgx
            const float Jd0 = J00 * dg0 + J01 * dg1 + J02 * dg2;
            const float Jd1 = J10 * dg0 + J11 * dg1 + J12 * dg2;
            const float Jd2 = J20 * dg0 + J21 * dg1 + J22 * dg2;
            const float a0 = dx0 - Jd0, a1 = dx1 - Jd1, a2 = dx2 - Jd2;
            float bden = v0 * dg0 + v1 * dg1 + v2 * dg2;
            bden += (bden >= 0.f) ? 1e-6f : -1e-6f;
            if (mask) {
                const float q0 = a0 / bden, q1 = a1 / bden, q2 = a2 / bden;
                J00 = fmaf(q0, v0, J00); J01 = fmaf(q0, v1, J01); J02 = fmaf(q0, v2, J02);
                J10 = fmaf(q1, v0, J10); J11 = fmaf(q1, v1, J11); J12 = fmaf(q1, v2, J12);
                J20 = fmaf(q2, v0, J20); J21 = fmaf(q2, v1, J21); J22 = fmaf(q2, v2, J22);
            }
            if (m3) {
                up0 = -(J00 * gx0 + J01 * gx1 + J02 * gx2);
                up1 = -(J10 * gx0 + J11 * gx1 + J12 * gx2);
                up2 = -(J20 * gx0 + J21 * gx1 + J22 * gx2);
            }
        }
        ++step;
    }
}

extern "C" void kernel_launch(void* const* d_in, const int* in_sizes, int n_in,
                              void* d_out, int out_size, void* d_ws, size_t ws_size,
                              hipStream_t stream) {
    const float* x = (const float*)d_in[0];
    const float* bone_pts = (const float*)d_in[1];
    const float* transforms = (const float*)d_in[2];
    const float* delta_tf = (const float*)d_in[3];
    const float* W0 = (const float*)d_in[4];
    const float* b0 = (const float*)d_in[5];
    const float* W1 = (const float*)d_in[6];
    const float* b1 = (const float*)d_in[7];
    const float* W2 = (const float*)d_in[8];
    const float* b2 = (const float*)d_in[9];
    const float* W3 = (const float*)d_in[10];
    const float* b3 = (const float*)d_in[11];
    const float* W4 = (const float*)d_in[12];
    const float* b4 = (const float*)d_in[13];
    float* out = (float*)d_out;

    const int Npts = in_sizes[0] / 3;
    const int M = Npts * 6;
    const int blocks = (M + BLOCK - 1) / BLOCK;
    snarf_kernel<<<blocks, BLOCK, 0, stream>>>(
        x, bone_pts, transforms, delta_tf, W0, b0, W1, b1, W2, b2, W3, b3, W4,
        b4, out, Npts);
}